// Round 2
// 272.415 us; speedup vs baseline: 1.0087x; 1.0087x over previous
//
#include <hip/hip_runtime.h>
#include <hip/hip_bf16.h>
#include <string.h>

typedef __attribute__((ext_vector_type(8))) short short8;
typedef __attribute__((ext_vector_type(4))) float floatx4;

// B=32, T=2048, D=512, U=512, M = B*T = 65536

__device__ inline uint packbf2(float lo, float hi) {
    __hip_bfloat162 h = __float22bfloat162_rn(make_float2(lo, hi));
    uint r; memcpy(&r, &h, 4); return r;
}

__device__ inline float tanh_fast(float x) {
    x = fminf(15.f, fmaxf(-15.f, x));
    float e = __expf(2.f * x);
    return __fdividef(e - 1.f, e + 1.f);
}

// ---- kernel 0a: pack W1_enc (512x512 fp32 [k][n]) -> bf16 MFMA B-frag chunks.
__global__ void kpack(const float* __restrict__ W1, ushort* __restrict__ Wp) {
    int wid = blockIdx.x * 4 + (threadIdx.x >> 6);   // 0..511 chunks
    int l = threadIdx.x & 63;
    int kc = wid >> 5, ng = wid & 31;
    int m = l & 15, g = l >> 4;
    const float* src = W1 + (size_t)(kc * 32 + g * 8) * 512 + ng * 16 + m;
    uint u4[4];
    #pragma unroll
    for (int e = 0; e < 4; ++e)
        u4[e] = packbf2(src[(size_t)(2 * e) * 512], src[(size_t)(2 * e + 1) * 512]);
    *(uint4*)(Wp + (size_t)wid * 512 + l * 8) = *(uint4*)u4;
}

// ---- kernel 0b: dec[b][u] = sum_d h_dec[b][d]*W1[512+d][u] + b1[u]
__global__ void kdec(const float* __restrict__ W1, const float* __restrict__ hdec,
                     const float* __restrict__ b1, float* __restrict__ dec) {
    __shared__ float red[4][64];
    int b = blockIdx.x >> 3, ug = blockIdx.x & 7;
    int tid = threadIdx.x;
    int u = ug * 64 + (tid & 63), dq = tid >> 6;
    const float* hb = hdec + b * 512 + dq * 128;
    const float* w = W1 + (size_t)(512 + dq * 128) * 512 + u;
    float a = 0.f;
    #pragma unroll 8
    for (int d = 0; d < 128; ++d)
        a += hb[d] * w[(size_t)d * 512];
    red[dq][tid & 63] = a;
    __syncthreads();
    if (tid < 64)
        dec[b * 512 + ug * 64 + tid] =
            red[0][tid] + red[1][tid] + red[2][tid] + red[3][tid] + b1[ug * 64 + tid];
}

// ---- kernel 1: fused GEMM + tanh + dot(W2) -> e2 (pre-relu logits)
// 512 thr = 8 waves; block tile 64 rows x 512 cols (full U) x K=512.
// K split into 4 chunks of 128, double-buffered LDS (2 x 16 KB),
// global loads for chunk c+2 issued under compute of chunk c (issue-early /
// write-late), and per-wave sub-kc rotation to decorrelate L2/MFMA phases.
__global__ __launch_bounds__(512, 4) void kgemm(
        const float* __restrict__ A, const ushort* __restrict__ Wp,
        const float* __restrict__ dec, const float* __restrict__ W2,
        float* __restrict__ e2) {
    __shared__ __align__(16) ushort Ab[2][8192];     // 2 x 16 KB (64 rows x 128 k bf16)
    __shared__ float red[8][64];                     // 2 KB
    const int tid = threadIdx.x;
    const int rowbase = blockIdx.x * 64;
    const int bIdx = blockIdx.x >> 5;                // 32 blocks per batch
    const int lane = tid & 63, wave = tid >> 6;
    const int m = lane & 15, g = lane >> 4;
    const int slot0 = tid >> 6;                      // staging slot for p=0

    float4 L[4];                                     // in-flight stage regs (16 VGPR)

    // issue 4 float4 global loads for chunk c (no wait here)
    auto load_chunk = [&](int c) {
        #pragma unroll
        for (int p = 0; p < 2; ++p) {
            int slot = slot0 + 8 * p;                // 0..15: slot = i*4 + kc4
            int i = slot >> 2, kc4 = slot & 3;
            const float* gp = A + (size_t)(rowbase + i * 16 + m) * 512
                              + (c * 4 + kc4) * 32 + g * 8;
            L[2 * p]     = *(const float4*)gp;
            L[2 * p + 1] = *(const float4*)(gp + 4);
        }
    };
    // cvt + LDS write of the regs loaded by the matching load_chunk
    auto write_chunk = [&](int cb) {
        #pragma unroll
        for (int p = 0; p < 2; ++p) {
            int slot = slot0 + 8 * p;
            uint4 u;
            u.x = packbf2(L[2 * p].x,     L[2 * p].y);
            u.y = packbf2(L[2 * p].z,     L[2 * p].w);
            u.z = packbf2(L[2 * p + 1].x, L[2 * p + 1].y);
            u.w = packbf2(L[2 * p + 1].z, L[2 * p + 1].w);
            *(uint4*)&Ab[cb][slot * 512 + lane * 8] = u;
        }
    };

    floatx4 acc[4][4];
    #pragma unroll
    for (int i = 0; i < 4; i++)
        #pragma unroll
        for (int j = 0; j < 4; j++) acc[i][j] = (floatx4){0.f, 0.f, 0.f, 0.f};

    const int ng0 = wave * 4;                        // wave covers cols wave*64..+63

    // prologue: buf0 <- chunk0, issue chunk1
    load_chunk(0);
    write_chunk(0);
    load_chunk(1);
    __syncthreads();

    for (int cc = 0; cc < 4; ++cc) {
        const int cb = cc & 1;
        // compute chunk cc: 4 sub-kc (K=32 each), rotated per wave
        for (int s = 0; s < 4; ++s) {
            const int kc4 = (s + wave) & 3;
            const int kc = cc * 4 + kc4;
            short8 bfr[4];
            #pragma unroll
            for (int j = 0; j < 4; ++j)
                bfr[j] = *(const short8*)&Wp[(size_t)(kc * 32 + ng0 + j) * 512 + lane * 8];
            #pragma unroll
            for (int i = 0; i < 4; ++i) {
                short8 afr = *(const short8*)&Ab[cb][(i * 4 + kc4) * 512 + lane * 8];
                #pragma unroll
                for (int j = 0; j < 4; ++j)
                    acc[i][j] = __builtin_amdgcn_mfma_f32_16x16x32_bf16(afr, bfr[j], acc[i][j], 0, 0, 0);
            }
        }
        if (cc < 3) {
            __syncthreads();                         // all waves done reading buf[(cc+1)&1]
            write_chunk((cc + 1) & 1);               // waits vmcnt for chunk cc+1 (long arrived)
            if (cc < 2) load_chunk(cc + 2);          // issue next loads -> overlap compute(cc+1)
            __syncthreads();                         // writes visible
        }
    }

    // epilogue: z += dec; p = sum_u tanh(z)*W2[u]; reduce 16 lanes + 8 waves
    float w2v[4], dv[4];
    #pragma unroll
    for (int j = 0; j < 4; j++) {
        int n = wave * 64 + j * 16 + m;
        w2v[j] = W2[n];
        dv[j]  = dec[bIdx * 512 + n];
    }
    #pragma unroll
    for (int i = 0; i < 4; i++) {
        #pragma unroll
        for (int r = 0; r < 4; r++) {
            float p = 0.f;
            #pragma unroll
            for (int j = 0; j < 4; j++)
                p += tanh_fast(acc[i][j][r] + dv[j]) * w2v[j];
            p += __shfl_xor(p, 1, 16);
            p += __shfl_xor(p, 2, 16);
            p += __shfl_xor(p, 4, 16);
            p += __shfl_xor(p, 8, 16);
            if (m == 0) red[wave][i * 16 + g * 4 + r] = p;
        }
    }
    __syncthreads();
    if (tid < 64) {
        float s = 0.f;
        #pragma unroll
        for (int w = 0; w < 8; ++w) s += red[w][tid];
        e2[rowbase + tid] = s;
    }
}

// ---- kernel 2: per-batch relu(+b2) + softmax over T -> attn
__global__ void ksoftmax(const float* __restrict__ e2, const float* __restrict__ b2,
                         float* __restrict__ attn) {
    int b = blockIdx.x, tid = threadIdx.x;
    int lane = tid & 63, wave = tid >> 6;
    float b2v = b2[0];
    float f[8];
    float mx = -1e30f;
    #pragma unroll
    for (int i = 0; i < 8; i++) {
        float z = e2[b * 2048 + i * 256 + tid] + b2v;
        f[i] = fmaxf(z, 0.f);
        mx = fmaxf(mx, f[i]);
    }
    #pragma unroll
    for (int off = 1; off < 64; off <<= 1) mx = fmaxf(mx, __shfl_xor(mx, off));
    __shared__ float red[4], red2[4];
    if (lane == 0) red[wave] = mx;
    __syncthreads();
    mx = fmaxf(fmaxf(red[0], red[1]), fmaxf(red[2], red[3]));
    float s = 0.f;
    #pragma unroll
    for (int i = 0; i < 8; i++) { f[i] = __expf(f[i] - mx); s += f[i]; }
    #pragma unroll
    for (int off = 1; off < 64; off <<= 1) s += __shfl_xor(s, off);
    if (lane == 0) red2[wave] = s;
    __syncthreads();
    s = red2[0] + red2[1] + red2[2] + red2[3];
    float inv = 1.f / s;
    #pragma unroll
    for (int i = 0; i < 8; i++)
        attn[b * 2048 + i * 256 + tid] = f[i] * inv;
}

// ---- kernel 3: partial context: part[b][ch][d] = sum_{t in 64-chunk} attn*h_enc
// 512 thr, 4-way T-split (16 t each, fully unrolled) -> 32 waves/CU,
// ~256 B of loads in flight per thread; should be HBM/L3-BW-bound now.
__global__ void kctx(const float* __restrict__ A, const float* __restrict__ attn,
                     float* __restrict__ part) {
    __shared__ float at[64];
    __shared__ float4 red[3][128];
    int b = blockIdx.x, ch = blockIdx.y, tid = threadIdx.x;
    if (tid < 64) at[tid] = attn[b * 2048 + ch * 64 + tid];
    __syncthreads();
    int dt = tid & 127, th = tid >> 7;               // th in 0..3, 16 t each
    const float* base = A + ((size_t)b * 2048 + ch * 64 + th * 16) * 512 + dt * 4;
    const float* aw = at + th * 16;
    float4 acc = (float4){0.f, 0.f, 0.f, 0.f};
    #pragma unroll
    for (int tt = 0; tt < 16; ++tt) {
        float a = aw[tt];
        float4 h = *(const float4*)(base + (size_t)tt * 512);
        acc.x += a * h.x; acc.y += a * h.y; acc.z += a * h.z; acc.w += a * h.w;
    }
    if (th) red[th - 1][dt] = acc;
    __syncthreads();
    if (th == 0) {
        float4 o0 = red[0][dt], o1 = red[1][dt], o2 = red[2][dt];
        float4 r;
        r.x = acc.x + o0.x + o1.x + o2.x;
        r.y = acc.y + o0.y + o1.y + o2.y;
        r.z = acc.z + o0.z + o1.z + o2.z;
        r.w = acc.w + o0.w + o1.w + o2.w;
        *(float4*)(part + ((size_t)b * 32 + ch) * 512 + dt * 4) = r;
    }
}

// ---- kernel 4: ctx[b][d] = sum_ch part[b][ch][d]
__global__ void kfin(const float* __restrict__ part, float* __restrict__ ctx) {
    int idx = blockIdx.x * 256 + threadIdx.x;        // 0..16383
    int b = idx >> 9, d = idx & 511;
    const float* p = part + (size_t)b * 32 * 512 + d;
    float s = 0.f;
    #pragma unroll
    for (int cI = 0; cI < 32; ++cI) s += p[cI * 512];
    ctx[idx] = s;
}

extern "C" void kernel_launch(void* const* d_in, const int* in_sizes, int n_in,
                              void* d_out, int out_size, void* d_ws, size_t ws_size,
                              hipStream_t stream) {
    const float* h_enc = (const float*)d_in[0];
    const float* h_dec = (const float*)d_in[1];
    const float* W1    = (const float*)d_in[2];
    const float* b1    = (const float*)d_in[3];
    const float* W2    = (const float*)d_in[4];
    const float* b2    = (const float*)d_in[5];
    float* out  = (float*)d_out;
    float* ctx  = out;              // 32*512
    float* attn = out + 32 * 512;   // 32*2048

    char* ws = (char*)d_ws;
    ushort* Wp = (ushort*)ws;                                    // 512 KB
    float* dec  = (float*)(ws + (512 * 512 * 2));                // 64 KB
    float* e2   = (float*)(ws + (512 * 512 * 2) + (32 * 512 * 4));              // 256 KB
    float* part = (float*)(ws + (512 * 512 * 2) + (32 * 512 * 4) + (65536 * 4)); // 2 MB

    kpack<<<128, 256, 0, stream>>>(W1, Wp);
    kdec<<<256, 256, 0, stream>>>(W1, h_dec, b1, dec);
    kgemm<<<1024, 512, 0, stream>>>(h_enc, Wp, dec, W2, e2);
    ksoftmax<<<32, 256, 0, stream>>>(e2, b2, attn);
    dim3 g3(32, 32);
    kctx<<<g3, 512, 0, stream>>>(h_enc, attn, part);
    kfin<<<64, 256, 0, stream>>>(part, ctx);
}